// Round 2
// baseline (1644.094 us; speedup 1.0000x reference)
//
#include <hip/hip_runtime.h>
#include <stdint.h>

// CaMoE block, MI355X gfx950. Inputs/outputs fp32 (per reference).
// Internals: bf16 MFMA GEMMs; routing-critical path uses 2-term bf16 split
// (3 MFMA passes) for ~fp32 accuracy so argmax winners match the np reference.

#define N_TOK 8192
#define C_DIM 1024
#define H_DIM 4096

typedef unsigned short u16;
typedef __attribute__((ext_vector_type(8))) short short8;
typedef __attribute__((ext_vector_type(4))) float floatx4;

__device__ __forceinline__ float b2f(u16 u) {
  union { unsigned u; float f; } v; v.u = ((unsigned)u) << 16; return v.f;
}
__device__ __forceinline__ u16 f2b(float f) {
  union { float f; unsigned u; } v; v.f = f;
  unsigned r = v.u + 0x7fffu + ((v.u >> 16) & 1u);  // RNE
  return (u16)(r >> 16);
}
__device__ __forceinline__ float sigf(float x) { return 1.f / (1.f + __expf(-x)); }

typedef __attribute__((address_space(3))) unsigned int lds_uint;
typedef const __attribute__((address_space(1))) unsigned int glob_uint;
__device__ __forceinline__ void gld16(u16* lds, const u16* g) {
  __builtin_amdgcn_global_load_lds((glob_uint*)g, (lds_uint*)lds, 16, 0, 0);
}
__device__ __forceinline__ floatx4 mf(short8 a, short8 b, floatx4 c) {
  return __builtin_amdgcn_mfma_f32_16x16x32_bf16(a, b, c, 0, 0, 0);
}
// stage two 16B chunks of a 128x32 bf16 tile (row-major, K-stride) into LDS
__device__ __forceinline__ void stage2(u16* s, const u16* g, int K, int base,
                                       int c0, int c1, int k0) {
  gld16(s + c0 * 8, g + (size_t)(base + (c0 >> 2)) * K + k0 + (c0 & 3) * 8);
  gld16(s + c1 * 8, g + (size_t)(base + (c1 >> 2)) * K + k0 + (c1 & 3) * 8);
}
__device__ __forceinline__ void frag4(short8* f, const u16* s, int wo, int fr, int fk) {
#pragma unroll
  for (int i = 0; i < 4; i++) f[i] = *(const short8*)(s + (wo + i * 16 + fr) * 32 + fk);
}

// ============ high-precision dual GEMM: gated = sigmoid(A@Wr) * (A@Wv) =======
// A, B split into (hi, lo) bf16; 3 MFMA passes each. Writes gated split hi/lo.
__global__ __launch_bounds__(256) void gemm_rv(
    const u16* __restrict__ Ahi, const u16* __restrict__ Alo,
    const u16* __restrict__ Brh, const u16* __restrict__ Brl,
    const u16* __restrict__ Bvh, const u16* __restrict__ Bvl,
    int K, int NC, u16* __restrict__ Ghi, u16* __restrict__ Glo) {
  __shared__ __align__(16) u16 sAh[4096], sAl[4096], sRh[4096], sRl[4096],
      sVh[4096], sVl[4096];
  const int tid = threadIdx.x, lane = tid & 63, wave = tid >> 6;
  const int rowbase = blockIdx.y * 128, colbase = blockIdx.x * 128;
  const int wm = (wave >> 1) * 64, wn = (wave & 1) * 64;
  floatx4 ar[4][4] = {}, av[4][4] = {};
  const int c0 = tid, c1 = tid + 256;
  for (int k0 = 0; k0 < K; k0 += 32) {
    __syncthreads();
    stage2(sAh, Ahi, K, rowbase, c0, c1, k0);
    stage2(sAl, Alo, K, rowbase, c0, c1, k0);
    stage2(sRh, Brh, K, colbase, c0, c1, k0);
    stage2(sRl, Brl, K, colbase, c0, c1, k0);
    stage2(sVh, Bvh, K, colbase, c0, c1, k0);
    stage2(sVl, Bvl, K, colbase, c0, c1, k0);
    __syncthreads();
    const int fr = lane & 15, fk = (lane >> 4) * 8;
    short8 ah[4], al[4], rh[4], rl[4], vh[4], vl[4];
    frag4(ah, sAh, wm, fr, fk); frag4(al, sAl, wm, fr, fk);
    frag4(rh, sRh, wn, fr, fk); frag4(rl, sRl, wn, fr, fk);
    frag4(vh, sVh, wn, fr, fk); frag4(vl, sVl, wn, fr, fk);
#pragma unroll
    for (int mi = 0; mi < 4; mi++)
#pragma unroll
      for (int ni = 0; ni < 4; ni++) {
        ar[mi][ni] = mf(ah[mi], rh[ni], ar[mi][ni]);
        ar[mi][ni] = mf(ah[mi], rl[ni], ar[mi][ni]);
        ar[mi][ni] = mf(al[mi], rh[ni], ar[mi][ni]);
        av[mi][ni] = mf(ah[mi], vh[ni], av[mi][ni]);
        av[mi][ni] = mf(ah[mi], vl[ni], av[mi][ni]);
        av[mi][ni] = mf(al[mi], vh[ni], av[mi][ni]);
      }
  }
  const int col0 = lane & 15, row0 = (lane >> 4) * 4;
#pragma unroll
  for (int mi = 0; mi < 4; mi++)
#pragma unroll
    for (int ni = 0; ni < 4; ni++)
#pragma unroll
      for (int r = 0; r < 4; r++) {
        const int row = rowbase + wm + mi * 16 + row0 + r;
        const int col = colbase + wn + ni * 16 + col0;
        const size_t idx = (size_t)row * NC + col;
        const float g = sigf(ar[mi][ni][r]) * av[mi][ni][r];
        const u16 h = f2b(g);
        Ghi[idx] = h;
        Glo[idx] = f2b(g - b2f(h));
      }
}

// ============ high-precision GEMM: Xnew = Xin(fp32) + A@Wo ====================
__global__ __launch_bounds__(256) void gemm_wo(
    const u16* __restrict__ Ahi, const u16* __restrict__ Alo,
    const u16* __restrict__ Bh, const u16* __restrict__ Bl,
    int K, int NC, const float* __restrict__ Xin, float* __restrict__ Xnew) {
  __shared__ __align__(16) u16 sAh[4096], sAl[4096], sBh[4096], sBl[4096];
  const int tid = threadIdx.x, lane = tid & 63, wave = tid >> 6;
  const int rowbase = blockIdx.y * 128, colbase = blockIdx.x * 128;
  const int wm = (wave >> 1) * 64, wn = (wave & 1) * 64;
  floatx4 acc[4][4] = {};
  const int c0 = tid, c1 = tid + 256;
  for (int k0 = 0; k0 < K; k0 += 32) {
    __syncthreads();
    stage2(sAh, Ahi, K, rowbase, c0, c1, k0);
    stage2(sAl, Alo, K, rowbase, c0, c1, k0);
    stage2(sBh, Bh, K, colbase, c0, c1, k0);
    stage2(sBl, Bl, K, colbase, c0, c1, k0);
    __syncthreads();
    const int fr = lane & 15, fk = (lane >> 4) * 8;
    short8 ah[4], al[4], bh[4], bl[4];
    frag4(ah, sAh, wm, fr, fk); frag4(al, sAl, wm, fr, fk);
    frag4(bh, sBh, wn, fr, fk); frag4(bl, sBl, wn, fr, fk);
#pragma unroll
    for (int mi = 0; mi < 4; mi++)
#pragma unroll
      for (int ni = 0; ni < 4; ni++) {
        acc[mi][ni] = mf(ah[mi], bh[ni], acc[mi][ni]);
        acc[mi][ni] = mf(ah[mi], bl[ni], acc[mi][ni]);
        acc[mi][ni] = mf(al[mi], bh[ni], acc[mi][ni]);
      }
  }
  const int col0 = lane & 15, row0 = (lane >> 4) * 4;
#pragma unroll
  for (int mi = 0; mi < 4; mi++)
#pragma unroll
    for (int ni = 0; ni < 4; ni++)
#pragma unroll
      for (int r = 0; r < 4; r++) {
        const int row = rowbase + wm + mi * 16 + row0 + r;
        const int col = colbase + wn + ni * 16 + col0;
        const size_t idx = (size_t)row * NC + col;
        Xnew[idx] = Xin[idx] + acc[mi][ni][r];
      }
}

// ============ plain bf16 GEMM (m97 structure) =================================
// EPI 0: Cout = bf16(acc); EPI 2: Cout = bf16(relu(acc)^2)
// EPI 3: if winner[row]==eidx: Dout = XnewR + acc*scale[row]   (fp32 out)
template <int EPI>
__global__ __launch_bounds__(256) void gemm128(
    const u16* __restrict__ A, const u16* __restrict__ BT, int K, int NC,
    u16* __restrict__ Cout, const float* __restrict__ XnewR,
    const int* __restrict__ winner, const float* __restrict__ scale, int eidx,
    float* __restrict__ Dout) {
  __shared__ __align__(16) u16 sA[4096], sB[4096];
  const int tid = threadIdx.x, lane = tid & 63, wave = tid >> 6;
  const int rowbase = blockIdx.y * 128, colbase = blockIdx.x * 128;
  const int wm = (wave >> 1) * 64, wn = (wave & 1) * 64;
  floatx4 acc[4][4] = {};
  const int c0 = tid, c1 = tid + 256;
  for (int k0 = 0; k0 < K; k0 += 32) {
    __syncthreads();
    stage2(sA, A, K, rowbase, c0, c1, k0);
    stage2(sB, BT, K, colbase, c0, c1, k0);
    __syncthreads();
    const int fr = lane & 15, fk = (lane >> 4) * 8;
    short8 af[4], bf[4];
    frag4(af, sA, wm, fr, fk);
    frag4(bf, sB, wn, fr, fk);
#pragma unroll
    for (int mi = 0; mi < 4; mi++)
#pragma unroll
      for (int ni = 0; ni < 4; ni++)
        acc[mi][ni] = mf(af[mi], bf[ni], acc[mi][ni]);
  }
  const int col0 = lane & 15, row0 = (lane >> 4) * 4;
#pragma unroll
  for (int mi = 0; mi < 4; mi++)
#pragma unroll
    for (int ni = 0; ni < 4; ni++)
#pragma unroll
      for (int r = 0; r < 4; r++) {
        const int row = rowbase + wm + mi * 16 + row0 + r;
        const int col = colbase + wn + ni * 16 + col0;
        const size_t idx = (size_t)row * NC + col;
        const float v = acc[mi][ni][r];
        if constexpr (EPI == 0) {
          Cout[idx] = f2b(v);
        } else if constexpr (EPI == 2) {
          const float t = v > 0.f ? v * v : 0.f;
          Cout[idx] = f2b(t);
        } else {
          if (winner[row] == eidx) Dout[idx] = XnewR[idx] + v * scale[row];
        }
      }
}

// ============ fp32 -> bf16 (hi [,lo]) transpose ==============================
template <bool LO>
__global__ __launch_bounds__(256) void transpose_split(
    const float* __restrict__ in, u16* __restrict__ outh, u16* __restrict__ outl,
    int R, int Cc) {
  __shared__ float tile[32][33];
  const int tx = threadIdx.x & 31, ty = threadIdx.x >> 5;
  const int bx = blockIdx.x * 32, by = blockIdx.y * 32;
#pragma unroll
  for (int i = 0; i < 32; i += 8)
    tile[ty + i][tx] = in[(size_t)(by + ty + i) * Cc + bx + tx];
  __syncthreads();
#pragma unroll
  for (int i = 0; i < 32; i += 8) {
    const float v = tile[tx][ty + i];
    const size_t o = (size_t)(bx + ty + i) * R + by + tx;
    const u16 h = f2b(v);
    outh[o] = h;
    if constexpr (LO) outl[o] = f2b(v - b2f(h));
  }
}

// ============ LayerNorm fp32 -> bf16 hi (+lo) ================================
__global__ __launch_bounds__(256) void ln_kernel(
    const float* __restrict__ x, const float* __restrict__ w,
    const float* __restrict__ b, u16* __restrict__ oh, u16* __restrict__ ol) {
  const int row = blockIdx.x, tid = threadIdx.x;
  const float* xr = x + (size_t)row * C_DIM;
  float vals[4], s = 0.f, ss = 0.f;
#pragma unroll
  for (int i = 0; i < 4; i++) {
    const float t = xr[tid + i * 256];
    vals[i] = t; s += t; ss += t * t;
  }
  for (int off = 32; off; off >>= 1) {
    s += __shfl_xor(s, off, 64);
    ss += __shfl_xor(ss, off, 64);
  }
  __shared__ float red[8];
  const int lane = tid & 63, wave = tid >> 6;
  if (lane == 0) { red[wave] = s; red[4 + wave] = ss; }
  __syncthreads();
  const float S = red[0] + red[1] + red[2] + red[3];
  const float SS = red[4] + red[5] + red[6] + red[7];
  const float mean = S * (1.f / C_DIM);
  const float var = SS * (1.f / C_DIM) - mean * mean;
  const float inv = rsqrtf(var + 1e-5f);
#pragma unroll
  for (int i = 0; i < 4; i++) {
    const int c = tid + i * 256;
    const float y = (vals[i] - mean) * inv * w[c] + b[c];
    const u16 h = f2b(y);
    oh[(size_t)row * C_DIM + c] = h;
    if (ol) ol[(size_t)row * C_DIM + c] = f2b(y - b2f(h));
  }
}

// ============ gate: out = bf16( sigmoid(a) * b ) =============================
__global__ __launch_bounds__(256) void gate_kernel(
    const u16* __restrict__ a, const u16* __restrict__ b, u16* __restrict__ out) {
  const size_t base = ((size_t)blockIdx.x * 256 + threadIdx.x) * 4;
  const ushort4 av = *(const ushort4*)(a + base);
  const ushort4 bv = *(const ushort4*)(b + base);
  ushort4 o;
  o.x = f2b(sigf(b2f(av.x)) * b2f(bv.x));
  o.y = f2b(sigf(b2f(av.y)) * b2f(bv.y));
  o.z = f2b(sigf(b2f(av.z)) * b2f(bv.z));
  o.w = f2b(sigf(b2f(av.w)) * b2f(bv.w));
  *(ushort4*)(out + base) = o;
}

// ============ routing: fp32 LN2 recompute + 7 dots + argmax ==================
__global__ __launch_bounds__(256) void route_kernel(
    const float* __restrict__ xn, const float* __restrict__ w2,
    const float* __restrict__ b2, const float* __restrict__ conf_rwkv,
    const float* __restrict__ conf_trans, const float* __restrict__ w_diff,
    const float* __restrict__ W_aff, const float* __restrict__ capital,
    int* __restrict__ winner, float* __restrict__ scale) {
  const int token = blockIdx.x * 4 + (threadIdx.x >> 6);
  const int lane = threadIdx.x & 63;
  const float* xr = xn + (size_t)token * C_DIM;
  float xv[16], s = 0.f, ss = 0.f;
#pragma unroll
  for (int j = 0; j < 16; j++) {
    const float t = xr[lane + j * 64];
    xv[j] = t; s += t; ss += t * t;
  }
  for (int off = 32; off; off >>= 1) {
    s += __shfl_xor(s, off, 64);
    ss += __shfl_xor(ss, off, 64);
  }
  const float mean = s * (1.f / C_DIM);
  const float var = ss * (1.f / C_DIM) - mean * mean;
  const float inv = rsqrtf(var + 1e-5f);
  float acc[7] = {};
#pragma unroll
  for (int j = 0; j < 16; j++) {
    const int c = lane + j * 64;
    const float hv = (xv[j] - mean) * inv * w2[c] + b2[c];
    acc[0] += hv * conf_rwkv[c];
    acc[1] += hv * conf_rwkv[C_DIM + c];
    acc[2] += hv * conf_trans[c];
    acc[3] += hv * w_diff[c];
    acc[4] += hv * W_aff[c * 3 + 0];
    acc[5] += hv * W_aff[c * 3 + 1];
    acc[6] += hv * W_aff[c * 3 + 2];
  }
  for (int off = 32; off; off >>= 1)
#pragma unroll
    for (int j = 0; j < 7; j++) acc[j] += __shfl_xor(acc[j], off, 64);
  if (lane == 0) {
    const float conf[3] = {1.f / (1.f + expf(-acc[0])), 1.f / (1.f + expf(-acc[1])),
                           1.f / (1.f + expf(-acc[2]))};
    const float diff = 1.f / (1.f + expf(-acc[3]));
    int best = 0; float bb = -1e30f;
#pragma unroll
    for (int e = 0; e < 3; e++) {
      const float bid = conf[e] * capital[e] * diff + acc[4 + e];
      if (bid > bb) { bb = bid; best = e; }  // first-max ties = jnp.argmax
    }
    winner[token] = best;
    scale[token] = conf[best] / (conf[best] + 1e-6f);
  }
}

extern "C" void kernel_launch(void* const* d_in, const int* in_sizes, int n_in,
                              void* d_out, int out_size, void* d_ws, size_t ws_size,
                              hipStream_t stream) {
  const float* x = (const float*)d_in[0];
  const float* capital = (const float*)d_in[2];
  const float* ln1w = (const float*)d_in[3];
  const float* ln1b = (const float*)d_in[4];
  const float* ln2w = (const float*)d_in[5];
  const float* ln2b = (const float*)d_in[6];
  const float* Wr = (const float*)d_in[7];
  const float* Wv = (const float*)d_in[8];
  const float* Wo = (const float*)d_in[9];
  const float* Wsm = (const float*)d_in[10];
  const float* Krwkv = (const float*)d_in[11];   // (2, C, H)
  const float* Vrwkv = (const float*)d_in[12];   // (2, H, C)
  const float* conf_rwkv = (const float*)d_in[13];
  const float* W1 = (const float*)d_in[14];
  const float* W2 = (const float*)d_in[15];
  const float* W3 = (const float*)d_in[16];
  const float* conf_trans = (const float*)d_in[17];
  const float* w_diff = (const float*)d_in[18];
  const float* W_aff = (const float*)d_in[19];
  float* out = (float*)d_out;

  char* ws = (char*)d_ws;
  size_t off = 0;
  auto alloc = [&](size_t bytes) -> char* {
    char* p = ws + off;
    off += (bytes + 255) & ~(size_t)255;
    return p;
  };
  const size_t CC = (size_t)C_DIM * C_DIM * 2;   // 2 MiB
  const size_t CH = (size_t)C_DIM * H_DIM * 2;   // 8 MiB
  const size_t NCb = (size_t)N_TOK * C_DIM * 2;  // 16 MiB
  u16* WrTh = (u16*)alloc(CC); u16* WrTl = (u16*)alloc(CC);
  u16* WvTh = (u16*)alloc(CC); u16* WvTl = (u16*)alloc(CC);
  u16* WoTh = (u16*)alloc(CC); u16* WoTl = (u16*)alloc(CC);
  u16* WsT = (u16*)alloc(CC);
  u16* W1T = (u16*)alloc(CC);
  u16* W2T = (u16*)alloc(CC);
  u16* W3T = (u16*)alloc(CC);
  u16* KT = (u16*)alloc(CH);   // reused per expert
  u16* VT = (u16*)alloc(CH);   // reused per expert
  u16* xlnh = (u16*)alloc(NCb);   // later: h_bf16
  u16* xlnl = (u16*)alloc(NCb);   // later: t2
  u16* ghi = (u16*)alloc(NCb);    // later: hr chunk
  u16* glo = (u16*)alloc(NCb);    // later: t1
  u16* stateb = (u16*)alloc(NCb); // later: tg
  float* x_new = (float*)alloc((size_t)N_TOK * C_DIM * 4);  // 32 MiB
  int* winner = (int*)alloc(N_TOK * 4);
  float* scalep = (float*)alloc(N_TOK * 4);

  const dim3 blk(256);
  // weight transposes (fp32 -> bf16 split / plain)
  const dim3 tCC(32, 32);
  transpose_split<true><<<tCC, blk, 0, stream>>>(Wr, WrTh, WrTl, C_DIM, C_DIM);
  transpose_split<true><<<tCC, blk, 0, stream>>>(Wv, WvTh, WvTl, C_DIM, C_DIM);
  transpose_split<true><<<tCC, blk, 0, stream>>>(Wo, WoTh, WoTl, C_DIM, C_DIM);
  transpose_split<false><<<tCC, blk, 0, stream>>>(Wsm, WsT, nullptr, C_DIM, C_DIM);
  transpose_split<false><<<tCC, blk, 0, stream>>>(W1, W1T, nullptr, C_DIM, C_DIM);
  transpose_split<false><<<tCC, blk, 0, stream>>>(W2, W2T, nullptr, C_DIM, C_DIM);
  transpose_split<false><<<tCC, blk, 0, stream>>>(W3, W3T, nullptr, C_DIM, C_DIM);

  // LN1 (split)
  ln_kernel<<<N_TOK, blk, 0, stream>>>(x, ln1w, ln1b, xlnh, xlnl);

  const dim3 gC(C_DIM / 128, N_TOK / 128);  // (8, 64)
  // gated = sigmoid(xln@Wr) * (xln@Wv), split output
  gemm_rv<<<gC, blk, 0, stream>>>(xlnh, xlnl, WrTh, WrTl, WvTh, WvTl,
                                  C_DIM, C_DIM, ghi, glo);
  // state = xln @ Ws (plain bf16)
  gemm128<0><<<gC, blk, 0, stream>>>(xlnh, WsT, C_DIM, C_DIM, stateb,
                                     nullptr, nullptr, nullptr, 0, nullptr);
  // x_new = x + gated @ Wo (fp32, high precision)
  gemm_wo<<<gC, blk, 0, stream>>>(ghi, glo, WoTh, WoTl, C_DIM, C_DIM, x, x_new);
  // h = LN2(x_new) -> bf16 (into xlnh)
  ln_kernel<<<N_TOK, blk, 0, stream>>>(x_new, ln2w, ln2b, xlnh, nullptr);
  // routing (fp32 LN2 recompute inside)
  route_kernel<<<N_TOK / 4, blk, 0, stream>>>(x_new, ln2w, ln2b, conf_rwkv,
      conf_trans, w_diff, W_aff, capital, winner, scalep);

  // transformer expert: t1 = h@W1 (->glo), t2 = state@W2 (->xlnl),
  // tg = t1*sigmoid(t2) (->stateb), out |= tg@W3 where winner==2
  gemm128<0><<<gC, blk, 0, stream>>>(xlnh, W1T, C_DIM, C_DIM, glo,
                                     nullptr, nullptr, nullptr, 0, nullptr);
  gemm128<0><<<gC, blk, 0, stream>>>(stateb, W2T, C_DIM, C_DIM, xlnl,
                                     nullptr, nullptr, nullptr, 0, nullptr);
  gate_kernel<<<(N_TOK * C_DIM) / 1024, blk, 0, stream>>>(xlnl, glo, stateb);
  gemm128<3><<<gC, blk, 0, stream>>>(stateb, W3T, C_DIM, C_DIM, nullptr,
                                     x_new, winner, scalep, 2, out);

  // RWKV experts, hr chunked into 4 slices of 2048 rows (hr lives in ghi)
  const int CHUNK = 2048;
  u16* hr = ghi;
  for (int e = 0; e < 2; e++) {
    const float* Ke = Krwkv + (size_t)e * C_DIM * H_DIM;
    const float* Ve = Vrwkv + (size_t)e * H_DIM * C_DIM;
    transpose_split<false><<<dim3(H_DIM / 32, C_DIM / 32), blk, 0, stream>>>(
        Ke, KT, nullptr, C_DIM, H_DIM);
    transpose_split<false><<<dim3(C_DIM / 32, H_DIM / 32), blk, 0, stream>>>(
        Ve, VT, nullptr, H_DIM, C_DIM);
    for (int ch = 0; ch < N_TOK / CHUNK; ch++) {
      const size_t ro = (size_t)ch * CHUNK;
      gemm128<2><<<dim3(H_DIM / 128, CHUNK / 128), blk, 0, stream>>>(
          xlnh + ro * C_DIM, KT, C_DIM, H_DIM, hr,
          nullptr, nullptr, nullptr, 0, nullptr);
      gemm128<3><<<dim3(C_DIM / 128, CHUNK / 128), blk, 0, stream>>>(
          hr, VT, H_DIM, C_DIM, nullptr,
          x_new + ro * C_DIM, winner + ro, scalep + ro, e, out + ro * C_DIM);
    }
  }
}

// Round 3
// 983.327 us; speedup vs baseline: 1.6720x; 1.6720x over previous
//
#include <hip/hip_runtime.h>
#include <stdint.h>

// CaMoE block, MI355X gfx950. fp32 in/out. bf16 MFMA internals; the
// routing-critical path (LN1 -> r,v -> gate -> @Wo -> x_new -> LN2 -> bids)
// uses 2-term bf16 split (3 MFMA passes) for ~fp32 accuracy so argmax winners
// match the np reference. Expert compute is ROUTED: tokens compacted per
// winner, gathered GEMMs with early-exit blocks (grids static for graph
// capture; counts read from device memory).

#define N_TOK 8192
#define C_DIM 1024
#define H_DIM 4096

typedef unsigned short u16;
typedef __attribute__((ext_vector_type(8))) short short8;
typedef __attribute__((ext_vector_type(4))) float floatx4;

__device__ __forceinline__ float b2f(u16 u) {
  union { unsigned u; float f; } v; v.u = ((unsigned)u) << 16; return v.f;
}
__device__ __forceinline__ u16 f2b(float f) {
  union { float f; unsigned u; } v; v.f = f;
  unsigned r = v.u + 0x7fffu + ((v.u >> 16) & 1u);  // RNE
  return (u16)(r >> 16);
}
__device__ __forceinline__ float sigf(float x) { return 1.f / (1.f + __expf(-x)); }

typedef __attribute__((address_space(3))) unsigned int lds_uint;
typedef const __attribute__((address_space(1))) unsigned int glob_uint;
__device__ __forceinline__ void gld16(u16* lds, const u16* g) {
  __builtin_amdgcn_global_load_lds((glob_uint*)g, (lds_uint*)lds, 16, 0, 0);
}
__device__ __forceinline__ floatx4 mf(short8 a, short8 b, floatx4 c) {
  return __builtin_amdgcn_mfma_f32_16x16x32_bf16(a, b, c, 0, 0, 0);
}
__device__ __forceinline__ void stage2(u16* s, const u16* g, int K, int base,
                                       int c0, int c1, int k0) {
  gld16(s + c0 * 8, g + (size_t)(base + (c0 >> 2)) * K + k0 + (c0 & 3) * 8);
  gld16(s + c1 * 8, g + (size_t)(base + (c1 >> 2)) * K + k0 + (c1 & 3) * 8);
}
__device__ __forceinline__ void frag4(short8* f, const u16* s, int wo, int fr, int fk) {
#pragma unroll
  for (int i = 0; i < 4; i++) f[i] = *(const short8*)(s + (wo + i * 16 + fr) * 32 + fk);
}

// ============ high-precision dual GEMM: gated = sigmoid(A@Wr) * (A@Wv) =======
__global__ __launch_bounds__(256) void gemm_rv(
    const u16* __restrict__ Ahi, const u16* __restrict__ Alo,
    const u16* __restrict__ Brh, const u16* __restrict__ Brl,
    const u16* __restrict__ Bvh, const u16* __restrict__ Bvl,
    int K, int NC, u16* __restrict__ Ghi, u16* __restrict__ Glo) {
  __shared__ __align__(16) u16 sAh[4096], sAl[4096], sRh[4096], sRl[4096],
      sVh[4096], sVl[4096];
  const int tid = threadIdx.x, lane = tid & 63, wave = tid >> 6;
  const int rowbase = blockIdx.y * 128, colbase = blockIdx.x * 128;
  const int wm = (wave >> 1) * 64, wn = (wave & 1) * 64;
  floatx4 ar[4][4] = {}, av[4][4] = {};
  const int c0 = tid, c1 = tid + 256;
  for (int k0 = 0; k0 < K; k0 += 32) {
    __syncthreads();
    stage2(sAh, Ahi, K, rowbase, c0, c1, k0);
    stage2(sAl, Alo, K, rowbase, c0, c1, k0);
    stage2(sRh, Brh, K, colbase, c0, c1, k0);
    stage2(sRl, Brl, K, colbase, c0, c1, k0);
    stage2(sVh, Bvh, K, colbase, c0, c1, k0);
    stage2(sVl, Bvl, K, colbase, c0, c1, k0);
    __syncthreads();
    const int fr = lane & 15, fk = (lane >> 4) * 8;
    short8 ah[4], al[4], rh[4], rl[4], vh[4], vl[4];
    frag4(ah, sAh, wm, fr, fk); frag4(al, sAl, wm, fr, fk);
    frag4(rh, sRh, wn, fr, fk); frag4(rl, sRl, wn, fr, fk);
    frag4(vh, sVh, wn, fr, fk); frag4(vl, sVl, wn, fr, fk);
#pragma unroll
    for (int mi = 0; mi < 4; mi++)
#pragma unroll
      for (int ni = 0; ni < 4; ni++) {
        ar[mi][ni] = mf(ah[mi], rh[ni], ar[mi][ni]);
        ar[mi][ni] = mf(ah[mi], rl[ni], ar[mi][ni]);
        ar[mi][ni] = mf(al[mi], rh[ni], ar[mi][ni]);
        av[mi][ni] = mf(ah[mi], vh[ni], av[mi][ni]);
        av[mi][ni] = mf(ah[mi], vl[ni], av[mi][ni]);
        av[mi][ni] = mf(al[mi], vh[ni], av[mi][ni]);
      }
  }
  const int col0 = lane & 15, row0 = (lane >> 4) * 4;
#pragma unroll
  for (int mi = 0; mi < 4; mi++)
#pragma unroll
    for (int ni = 0; ni < 4; ni++)
#pragma unroll
      for (int r = 0; r < 4; r++) {
        const int row = rowbase + wm + mi * 16 + row0 + r;
        const int col = colbase + wn + ni * 16 + col0;
        const size_t idx = (size_t)row * NC + col;
        const float g = sigf(ar[mi][ni][r]) * av[mi][ni][r];
        const u16 h = f2b(g);
        Ghi[idx] = h;
        Glo[idx] = f2b(g - b2f(h));
      }
}

// ============ high-precision GEMM: Xnew = Xin(fp32) + A@Wo ====================
__global__ __launch_bounds__(256) void gemm_wo(
    const u16* __restrict__ Ahi, const u16* __restrict__ Alo,
    const u16* __restrict__ Bh, const u16* __restrict__ Bl,
    int K, int NC, const float* __restrict__ Xin, float* __restrict__ Xnew) {
  __shared__ __align__(16) u16 sAh[4096], sAl[4096], sBh[4096], sBl[4096];
  const int tid = threadIdx.x, lane = tid & 63, wave = tid >> 6;
  const int rowbase = blockIdx.y * 128, colbase = blockIdx.x * 128;
  const int wm = (wave >> 1) * 64, wn = (wave & 1) * 64;
  floatx4 acc[4][4] = {};
  const int c0 = tid, c1 = tid + 256;
  for (int k0 = 0; k0 < K; k0 += 32) {
    __syncthreads();
    stage2(sAh, Ahi, K, rowbase, c0, c1, k0);
    stage2(sAl, Alo, K, rowbase, c0, c1, k0);
    stage2(sBh, Bh, K, colbase, c0, c1, k0);
    stage2(sBl, Bl, K, colbase, c0, c1, k0);
    __syncthreads();
    const int fr = lane & 15, fk = (lane >> 4) * 8;
    short8 ah[4], al[4], bh[4], bl[4];
    frag4(ah, sAh, wm, fr, fk); frag4(al, sAl, wm, fr, fk);
    frag4(bh, sBh, wn, fr, fk); frag4(bl, sBl, wn, fr, fk);
#pragma unroll
    for (int mi = 0; mi < 4; mi++)
#pragma unroll
      for (int ni = 0; ni < 4; ni++) {
        acc[mi][ni] = mf(ah[mi], bh[ni], acc[mi][ni]);
        acc[mi][ni] = mf(ah[mi], bl[ni], acc[mi][ni]);
        acc[mi][ni] = mf(al[mi], bh[ni], acc[mi][ni]);
      }
  }
  const int col0 = lane & 15, row0 = (lane >> 4) * 4;
#pragma unroll
  for (int mi = 0; mi < 4; mi++)
#pragma unroll
    for (int ni = 0; ni < 4; ni++)
#pragma unroll
      for (int r = 0; r < 4; r++) {
        const int row = rowbase + wm + mi * 16 + row0 + r;
        const int col = colbase + wn + ni * 16 + col0;
        const size_t idx = (size_t)row * NC + col;
        Xnew[idx] = Xin[idx] + acc[mi][ni][r];
      }
}

// ============ gathered / scattered plain bf16 GEMM ===========================
// cnt = *cntp - base active local rows (blocks past cnt exit; static grid).
// A row gather via idxA (nullptr = identity). Padded idx entries are 0.
// EPI 0: Cout = bf16(acc)              (unconditional; buffer sized for tiles)
// EPI 2: Cout = bf16(relu(acc)^2)
// EPI 3: scatter: g=idxO[base+row]; out[g]=x_new[g]+acc*scale[g]  (row<cnt)
template <int EPI>
__global__ __launch_bounds__(256) void ggemm(
    const u16* __restrict__ A, const int* __restrict__ idxA,
    const u16* __restrict__ BT, int K, int NC,
    const int* __restrict__ cntp, int base,
    u16* __restrict__ Cout,
    const float* __restrict__ x_new, const float* __restrict__ scalep,
    const int* __restrict__ idxO, float* __restrict__ out) {
  const int cnt = cntp ? (*cntp - base) : (int)(gridDim.y * 128);
  if ((int)blockIdx.y * 128 >= cnt) return;
  __shared__ __align__(16) u16 sA[4096], sB[4096];
  const int tid = threadIdx.x, lane = tid & 63, wave = tid >> 6;
  const int rowbase = blockIdx.y * 128, colbase = blockIdx.x * 128;
  const int wm = (wave >> 1) * 64, wn = (wave & 1) * 64;
  floatx4 acc[4][4] = {};
  const int c0 = tid, c1 = tid + 256;
  const int r0 = rowbase + (c0 >> 2), r1 = rowbase + (c1 >> 2);
  const int g0 = idxA ? idxA[base + r0] : r0;
  const int g1 = idxA ? idxA[base + r1] : r1;
  const u16* pA0 = A + (size_t)g0 * K + (c0 & 3) * 8;
  const u16* pA1 = A + (size_t)g1 * K + (c1 & 3) * 8;
  const u16* pB0 = BT + (size_t)(colbase + (c0 >> 2)) * K + (c0 & 3) * 8;
  const u16* pB1 = BT + (size_t)(colbase + (c1 >> 2)) * K + (c1 & 3) * 8;
  for (int k0 = 0; k0 < K; k0 += 32) {
    __syncthreads();
    gld16(sA + c0 * 8, pA0 + k0);
    gld16(sA + c1 * 8, pA1 + k0);
    gld16(sB + c0 * 8, pB0 + k0);
    gld16(sB + c1 * 8, pB1 + k0);
    __syncthreads();
    const int fr = lane & 15, fk = (lane >> 4) * 8;
    short8 af[4], bf[4];
    frag4(af, sA, wm, fr, fk);
    frag4(bf, sB, wn, fr, fk);
#pragma unroll
    for (int mi = 0; mi < 4; mi++)
#pragma unroll
      for (int ni = 0; ni < 4; ni++)
        acc[mi][ni] = mf(af[mi], bf[ni], acc[mi][ni]);
  }
  const int col0 = lane & 15, row00 = (lane >> 4) * 4;
#pragma unroll
  for (int mi = 0; mi < 4; mi++)
#pragma unroll
    for (int ni = 0; ni < 4; ni++)
#pragma unroll
      for (int r = 0; r < 4; r++) {
        const int row = rowbase + wm + mi * 16 + row00 + r;
        const int col = colbase + wn + ni * 16 + col0;
        const float v = acc[mi][ni][r];
        if constexpr (EPI == 0) {
          Cout[(size_t)row * NC + col] = f2b(v);
        } else if constexpr (EPI == 2) {
          const float t = v > 0.f ? v * v : 0.f;
          Cout[(size_t)row * NC + col] = f2b(t);
        } else {
          if (row < cnt) {
            const int g = idxO[base + row];
            const size_t o = (size_t)g * NC + col;
            out[o] = x_new[o] + v * scalep[g];
          }
        }
      }
}

// ============ fp32 -> bf16 (hi [,lo]) transpose ==============================
template <bool LO>
__global__ __launch_bounds__(256) void transpose_split(
    const float* __restrict__ in, u16* __restrict__ outh, u16* __restrict__ outl,
    int R, int Cc) {
  __shared__ float tile[32][33];
  const int tx = threadIdx.x & 31, ty = threadIdx.x >> 5;
  const int bx = blockIdx.x * 32, by = blockIdx.y * 32;
#pragma unroll
  for (int i = 0; i < 32; i += 8)
    tile[ty + i][tx] = in[(size_t)(by + ty + i) * Cc + bx + tx];
  __syncthreads();
#pragma unroll
  for (int i = 0; i < 32; i += 8) {
    const float v = tile[tx][ty + i];
    const size_t o = (size_t)(bx + ty + i) * R + by + tx;
    const u16 h = f2b(v);
    outh[o] = h;
    if constexpr (LO) outl[o] = f2b(v - b2f(h));
  }
}

// ============ fp32 -> bf16 straight cast =====================================
__global__ __launch_bounds__(256) void cast_kernel(const float* __restrict__ in,
                                                   u16* __restrict__ o, int n) {
  const int i = blockIdx.x * 256 + threadIdx.x;
  if (i < n) o[i] = f2b(in[i]);
}

// ============ LayerNorm fp32 -> bf16 hi + lo (LN1) ===========================
__global__ __launch_bounds__(256) void ln_kernel(
    const float* __restrict__ x, const float* __restrict__ w,
    const float* __restrict__ b, u16* __restrict__ oh, u16* __restrict__ ol) {
  const int row = blockIdx.x, tid = threadIdx.x;
  const float* xr = x + (size_t)row * C_DIM;
  float vals[4], s = 0.f, ss = 0.f;
#pragma unroll
  for (int i = 0; i < 4; i++) {
    const float t = xr[tid + i * 256];
    vals[i] = t; s += t; ss += t * t;
  }
  for (int off = 32; off; off >>= 1) {
    s += __shfl_xor(s, off, 64);
    ss += __shfl_xor(ss, off, 64);
  }
  __shared__ float red[8];
  const int lane = tid & 63, wave = tid >> 6;
  if (lane == 0) { red[wave] = s; red[4 + wave] = ss; }
  __syncthreads();
  const float S = red[0] + red[1] + red[2] + red[3];
  const float SS = red[4] + red[5] + red[6] + red[7];
  const float mean = S * (1.f / C_DIM);
  const float var = SS * (1.f / C_DIM) - mean * mean;
  const float inv = rsqrtf(var + 1e-5f);
#pragma unroll
  for (int i = 0; i < 4; i++) {
    const int c = tid + i * 256;
    const float y = (vals[i] - mean) * inv * w[c] + b[c];
    const u16 h = f2b(y);
    oh[(size_t)row * C_DIM + c] = h;
    ol[(size_t)row * C_DIM + c] = f2b(y - b2f(h));
  }
}

// ============ gate: out = bf16( sigmoid(a) * b ) =============================
__global__ __launch_bounds__(256) void gate_kernel(
    const u16* __restrict__ a, const u16* __restrict__ b, u16* __restrict__ out) {
  const size_t base = ((size_t)blockIdx.x * 256 + threadIdx.x) * 4;
  const ushort4 av = *(const ushort4*)(a + base);
  const ushort4 bv = *(const ushort4*)(b + base);
  ushort4 o;
  o.x = f2b(sigf(b2f(av.x)) * b2f(bv.x));
  o.y = f2b(sigf(b2f(av.y)) * b2f(bv.y));
  o.z = f2b(sigf(b2f(av.z)) * b2f(bv.z));
  o.w = f2b(sigf(b2f(av.w)) * b2f(bv.w));
  *(ushort4*)(out + base) = o;
}

// ============ routing: fp32 LN2 + 7 dots + argmax; also emits h (bf16) =======
__global__ __launch_bounds__(256) void route_kernel(
    const float* __restrict__ xn, const float* __restrict__ w2,
    const float* __restrict__ b2, const float* __restrict__ conf_rwkv,
    const float* __restrict__ conf_trans, const float* __restrict__ w_diff,
    const float* __restrict__ W_aff, const float* __restrict__ capital,
    int* __restrict__ winner, float* __restrict__ scale, u16* __restrict__ oh) {
  const int token = blockIdx.x * 4 + (threadIdx.x >> 6);
  const int lane = threadIdx.x & 63;
  const float* xr = xn + (size_t)token * C_DIM;
  float xv[16], s = 0.f, ss = 0.f;
#pragma unroll
  for (int j = 0; j < 16; j++) {
    const float t = xr[lane + j * 64];
    xv[j] = t; s += t; ss += t * t;
  }
  for (int off = 32; off; off >>= 1) {
    s += __shfl_xor(s, off, 64);
    ss += __shfl_xor(ss, off, 64);
  }
  const float mean = s * (1.f / C_DIM);
  const float var = ss * (1.f / C_DIM) - mean * mean;
  const float inv = rsqrtf(var + 1e-5f);
  float acc[7] = {};
#pragma unroll
  for (int j = 0; j < 16; j++) {
    const int c = lane + j * 64;
    const float hv = (xv[j] - mean) * inv * w2[c] + b2[c];
    oh[(size_t)token * C_DIM + c] = f2b(hv);
    acc[0] += hv * conf_rwkv[c];
    acc[1] += hv * conf_rwkv[C_DIM + c];
    acc[2] += hv * conf_trans[c];
    acc[3] += hv * w_diff[c];
    acc[4] += hv * W_aff[c * 3 + 0];
    acc[5] += hv * W_aff[c * 3 + 1];
    acc[6] += hv * W_aff[c * 3 + 2];
  }
  for (int off = 32; off; off >>= 1)
#pragma unroll
    for (int j = 0; j < 7; j++) acc[j] += __shfl_xor(acc[j], off, 64);
  if (lane == 0) {
    const float conf[3] = {1.f / (1.f + expf(-acc[0])), 1.f / (1.f + expf(-acc[1])),
                           1.f / (1.f + expf(-acc[2]))};
    const float diff = 1.f / (1.f + expf(-acc[3]));
    int best = 0; float bb = -1e30f;
#pragma unroll
    for (int e = 0; e < 3; e++) {
      const float bid = conf[e] * capital[e] * diff + acc[4 + e];
      if (bid > bb) { bb = bid; best = e; }  // first-max ties = jnp.argmax
    }
    winner[token] = best;
    scale[token] = conf[best] / (conf[best] + 1e-6f);
  }
}

// ============ routing compaction =============================================
__global__ __launch_bounds__(256) void zero_kernel(int* __restrict__ p, int n) {
  const int i = blockIdx.x * 256 + threadIdx.x;
  if (i < n) p[i] = 0;
}
__global__ __launch_bounds__(256) void compact_kernel(
    const int* __restrict__ winner, int* __restrict__ idx, int* __restrict__ counts) {
  const int t = blockIdx.x * 256 + threadIdx.x;
  const int w = winner[t];
  const int pos = atomicAdd(counts + w, 1);
  idx[w * N_TOK + pos] = t;
}

extern "C" void kernel_launch(void* const* d_in, const int* in_sizes, int n_in,
                              void* d_out, int out_size, void* d_ws, size_t ws_size,
                              hipStream_t stream) {
  const float* x = (const float*)d_in[0];
  const float* capital = (const float*)d_in[2];
  const float* ln1w = (const float*)d_in[3];
  const float* ln1b = (const float*)d_in[4];
  const float* ln2w = (const float*)d_in[5];
  const float* ln2b = (const float*)d_in[6];
  const float* Wr = (const float*)d_in[7];
  const float* Wv = (const float*)d_in[8];
  const float* Wo = (const float*)d_in[9];
  const float* Wsm = (const float*)d_in[10];
  const float* Krwkv = (const float*)d_in[11];   // (2, C, H)
  const float* Vrwkv = (const float*)d_in[12];   // (2, H, C)
  const float* conf_rwkv = (const float*)d_in[13];
  const float* W1 = (const float*)d_in[14];
  const float* W2 = (const float*)d_in[15];
  const float* W3 = (const float*)d_in[16];
  const float* conf_trans = (const float*)d_in[17];
  const float* w_diff = (const float*)d_in[18];
  const float* W_aff = (const float*)d_in[19];
  float* out = (float*)d_out;

  char* ws = (char*)d_ws;
  size_t off = 0;
  auto alloc = [&](size_t bytes) -> char* {
    char* p = ws + off;
    off += (bytes + 255) & ~(size_t)255;
    return p;
  };
  const size_t CC = (size_t)C_DIM * C_DIM * 2;   // 2 MiB
  const size_t CH = (size_t)C_DIM * H_DIM * 2;   // 8 MiB
  const size_t NCb = (size_t)N_TOK * C_DIM * 2;  // 16 MiB
  u16* WrTh = (u16*)alloc(CC); u16* WrTl = (u16*)alloc(CC);
  u16* WvTh = (u16*)alloc(CC); u16* WvTl = (u16*)alloc(CC);
  u16* WoTh = (u16*)alloc(CC); u16* WoTl = (u16*)alloc(CC);
  u16* W1T = (u16*)alloc(CC);
  u16* W2T = (u16*)alloc(CC);
  u16* W3T = (u16*)alloc(CC);
  u16* Wsb = (u16*)alloc(CC);   // Ws row-major bf16
  u16* MT  = (u16*)alloc(CC);   // (Ws@W2)^T = W2T @ Ws
  u16* KT0 = (u16*)alloc(CH);
  u16* VT0 = (u16*)alloc(CH);
  u16* KT1 = (u16*)alloc(CH);
  u16* VT1 = (u16*)alloc(CH);
  u16* xlnh = (u16*)alloc(NCb);   // LN1 hi; later hr chunk (spans xlnh+xlnl)
  u16* xlnl = (u16*)alloc(NCb);   // LN1 lo; later t2
  u16* ghi = (u16*)alloc(NCb);    // gated hi; later h (bf16)
  u16* glo = (u16*)alloc(NCb);    // gated lo; later t1 / tg
  float* x_new = (float*)alloc((size_t)N_TOK * C_DIM * 4);  // 32 MiB
  int* idx = (int*)alloc(3 * N_TOK * 4);
  int* counts = (int*)alloc(256);
  int* winner = (int*)alloc(N_TOK * 4);
  float* scalep = (float*)alloc(N_TOK * 4);
  u16* hrbuf = xlnh;  // 32 MiB region (xlnh+xlnl), used after transformer done

  const dim3 blk(256);
  const dim3 tCC(32, 32);
  transpose_split<true><<<tCC, blk, 0, stream>>>(Wr, WrTh, WrTl, C_DIM, C_DIM);
  transpose_split<true><<<tCC, blk, 0, stream>>>(Wv, WvTh, WvTl, C_DIM, C_DIM);
  transpose_split<true><<<tCC, blk, 0, stream>>>(Wo, WoTh, WoTl, C_DIM, C_DIM);
  transpose_split<false><<<tCC, blk, 0, stream>>>(W1, W1T, nullptr, C_DIM, C_DIM);
  transpose_split<false><<<tCC, blk, 0, stream>>>(W2, W2T, nullptr, C_DIM, C_DIM);
  transpose_split<false><<<tCC, blk, 0, stream>>>(W3, W3T, nullptr, C_DIM, C_DIM);
  cast_kernel<<<(C_DIM * C_DIM) / 256, blk, 0, stream>>>(Wsm, Wsb, C_DIM * C_DIM);
  transpose_split<false><<<dim3(H_DIM / 32, C_DIM / 32), blk, 0, stream>>>(
      Krwkv, KT0, nullptr, C_DIM, H_DIM);
  transpose_split<false><<<dim3(C_DIM / 32, H_DIM / 32), blk, 0, stream>>>(
      Vrwkv, VT0, nullptr, H_DIM, C_DIM);
  transpose_split<false><<<dim3(H_DIM / 32, C_DIM / 32), blk, 0, stream>>>(
      Krwkv + (size_t)C_DIM * H_DIM, KT1, nullptr, C_DIM, H_DIM);
  transpose_split<false><<<dim3(C_DIM / 32, H_DIM / 32), blk, 0, stream>>>(
      Vrwkv + (size_t)C_DIM * H_DIM, VT1, nullptr, H_DIM, C_DIM);
  // MT = W2T @ Ws  (so t2 = xln_g @ (Ws@W2) uses BT=MT)
  ggemm<0><<<dim3(8, 8), blk, 0, stream>>>(W2T, nullptr, Wsb, C_DIM, C_DIM,
      nullptr, 0, MT, nullptr, nullptr, nullptr, nullptr);

  // LN1 (split)
  ln_kernel<<<N_TOK, blk, 0, stream>>>(x, ln1w, ln1b, xlnh, xlnl);

  const dim3 gC(C_DIM / 128, N_TOK / 128);  // (8, 64)
  gemm_rv<<<gC, blk, 0, stream>>>(xlnh, xlnl, WrTh, WrTl, WvTh, WvTl,
                                  C_DIM, C_DIM, ghi, glo);
  gemm_wo<<<gC, blk, 0, stream>>>(ghi, glo, WoTh, WoTl, C_DIM, C_DIM, x, x_new);
  // route: winner/scale + h (bf16 into ghi; ghi free after gemm_wo)
  route_kernel<<<N_TOK / 4, blk, 0, stream>>>(x_new, ln2w, ln2b, conf_rwkv,
      conf_trans, w_diff, W_aff, capital, winner, scalep, ghi);
  u16* hb = ghi;
  // compaction
  zero_kernel<<<(3 * N_TOK + 3 + 255) / 256, blk, 0, stream>>>(idx, 3 * N_TOK + 3);
  compact_kernel<<<N_TOK / 256, blk, 0, stream>>>(winner, idx, counts);

  // ---- transformer expert (e=2), gathered ----
  int* idx2 = idx + 2 * N_TOK;
  // t1 = gather(h)@W1 -> glo
  ggemm<0><<<gC, blk, 0, stream>>>(hb, idx2, W1T, C_DIM, C_DIM,
      counts + 2, 0, glo, nullptr, nullptr, nullptr, nullptr);
  // t2 = gather(xln_hi)@(Ws@W2) -> xlnl
  ggemm<0><<<gC, blk, 0, stream>>>(xlnh, idx2, MT, C_DIM, C_DIM,
      counts + 2, 0, xlnl, nullptr, nullptr, nullptr, nullptr);
  // tg = t1 * sigmoid(t2) -> glo (in-place elementwise)
  gate_kernel<<<(N_TOK * C_DIM) / 1024, blk, 0, stream>>>(xlnl, glo, glo);
  // out rows = x_new + (tg@W3)*scale, scattered
  ggemm<3><<<gC, blk, 0, stream>>>(glo, nullptr, W3T, C_DIM, C_DIM,
      counts + 2, 0, nullptr, x_new, scalep, idx2, out);

  // ---- RWKV experts (e=0,1), gathered, hr chunked 4096 rows ----
  const u16* KT[2] = {KT0, KT1};
  const u16* VT[2] = {VT0, VT1};
  for (int e = 0; e < 2; e++) {
    int* idxe = idx + e * N_TOK;
    for (int c = 0; c < 2; c++) {
      const int base = c * 4096;
      ggemm<2><<<dim3(H_DIM / 128, 32), blk, 0, stream>>>(
          hb, idxe, KT[e], C_DIM, H_DIM, counts + e, base, hrbuf,
          nullptr, nullptr, nullptr, nullptr);
      ggemm<3><<<dim3(C_DIM / 128, 32), blk, 0, stream>>>(
          hrbuf, nullptr, VT[e], H_DIM, C_DIM, counts + e, base, nullptr,
          x_new, scalep, idxe, out);
    }
  }
}

// Round 4
// 981.586 us; speedup vs baseline: 1.6749x; 1.0018x over previous
//
#include <hip/hip_runtime.h>
#include <stdint.h>

// CaMoE block, MI355X gfx950. fp32 in/out. bf16/fp16 MFMA internals.
// Routing bids computed via exact decomposition:
//   h.w_j = [x.(g*w_j) + gated.(Wo@(g*w_j))]/sigma - (m/sigma)*sum(g*w_j) + sum(b*w_j)
// so only gemm_rv needs hp (2-term bf16 split); Wo GEMM is 1-pass fp16.
// Expert compute is routed (compaction + gathered GEMMs, early-exit blocks).

#define N_TOK 8192
#define C_DIM 1024
#define H_DIM 4096

typedef unsigned short u16;
typedef __attribute__((ext_vector_type(8))) short short8;
typedef _Float16 half8 __attribute__((ext_vector_type(8)));
typedef __attribute__((ext_vector_type(4))) float floatx4;

__device__ __forceinline__ float b2f(u16 u) {
  union { unsigned u; float f; } v; v.u = ((unsigned)u) << 16; return v.f;
}
__device__ __forceinline__ u16 f2b(float f) {
  union { float f; unsigned u; } v; v.f = f;
  unsigned r = v.u + 0x7fffu + ((v.u >> 16) & 1u);  // RNE
  return (u16)(r >> 16);
}
__device__ __forceinline__ u16 f2h(float f) {
  union { _Float16 h; u16 u; } v; v.h = (_Float16)f; return v.u;
}
__device__ __forceinline__ float sigf(float x) { return 1.f / (1.f + __expf(-x)); }

typedef __attribute__((address_space(3))) unsigned int lds_uint;
typedef const __attribute__((address_space(1))) unsigned int glob_uint;
__device__ __forceinline__ void gld16(u16* lds, const u16* g) {
  __builtin_amdgcn_global_load_lds((glob_uint*)g, (lds_uint*)lds, 16, 0, 0);
}
__device__ __forceinline__ floatx4 mf(short8 a, short8 b, floatx4 c) {
  return __builtin_amdgcn_mfma_f32_16x16x32_bf16(a, b, c, 0, 0, 0);
}
__device__ __forceinline__ floatx4 mfh(half8 a, half8 b, floatx4 c) {
  return __builtin_amdgcn_mfma_f32_16x16x32_f16(a, b, c, 0, 0, 0);
}
// stage two 16B chunks of a 128x32 tile (c0=tid, c1=tid+256)
__device__ __forceinline__ void stage2(u16* s, const u16* g, int K, int base,
                                       int c0, int c1, int k0) {
  gld16(s + c0 * 8, g + (size_t)(base + (c0 >> 2)) * K + k0 + (c0 & 3) * 8);
  gld16(s + c1 * 8, g + (size_t)(base + (c1 >> 2)) * K + k0 + (c1 & 3) * 8);
}
// stage one 16B chunk of a 64x32 tile (c=tid in 0..255)
__device__ __forceinline__ void stage1(u16* s, const u16* g, int K, int base,
                                       int c, int k0) {
  gld16(s + c * 8, g + (size_t)(base + (c >> 2)) * K + k0 + (c & 3) * 8);
}
template <typename V>
__device__ __forceinline__ void fragN(V* f, const u16* s, int wo, int fr, int fk, int n) {
  for (int i = 0; i < n; i++) f[i] = *(const V*)(s + (wo + i * 16 + fr) * 32 + fk);
}

// ============ hp dual GEMM: gated = sigmoid(A@Wr) * (A@Wv), tile 128x64 ======
// Writes gated hi/lo (bf16 pair, for exact routing dots) + g16 (fp16, Wo GEMM A).
__global__ __launch_bounds__(256) void gemm_rv(
    const u16* __restrict__ Ahi, const u16* __restrict__ Alo,
    const u16* __restrict__ Brh, const u16* __restrict__ Brl,
    const u16* __restrict__ Bvh, const u16* __restrict__ Bvl,
    int K, int NC, u16* __restrict__ Ghi, u16* __restrict__ Glo,
    u16* __restrict__ G16) {
  __shared__ __align__(16) u16 sAh[4096], sAl[4096];
  __shared__ __align__(16) u16 sRh[2048], sRl[2048], sVh[2048], sVl[2048];
  const int tid = threadIdx.x, lane = tid & 63, wave = tid >> 6;
  const int rowbase = blockIdx.y * 128, colbase = blockIdx.x * 64;
  const int wm = (wave >> 1) * 64, wn = (wave & 1) * 32;
  floatx4 ar[4][2] = {}, av[4][2] = {};
  const int c0 = tid, c1 = tid + 256;
  for (int k0 = 0; k0 < K; k0 += 32) {
    __syncthreads();
    stage2(sAh, Ahi, K, rowbase, c0, c1, k0);
    stage2(sAl, Alo, K, rowbase, c0, c1, k0);
    stage1(sRh, Brh, K, colbase, c0, k0);
    stage1(sRl, Brl, K, colbase, c0, k0);
    stage1(sVh, Bvh, K, colbase, c0, k0);
    stage1(sVl, Bvl, K, colbase, c0, k0);
    __syncthreads();
    const int fr = lane & 15, fk = (lane >> 4) * 8;
    short8 ah[4], al[4], rh[2], rl[2], vh[2], vl[2];
    fragN(ah, sAh, wm, fr, fk, 4); fragN(al, sAl, wm, fr, fk, 4);
    fragN(rh, sRh, wn, fr, fk, 2); fragN(rl, sRl, wn, fr, fk, 2);
    fragN(vh, sVh, wn, fr, fk, 2); fragN(vl, sVl, wn, fr, fk, 2);
#pragma unroll
    for (int mi = 0; mi < 4; mi++)
#pragma unroll
      for (int ni = 0; ni < 2; ni++) {
        ar[mi][ni] = mf(ah[mi], rh[ni], ar[mi][ni]);
        ar[mi][ni] = mf(ah[mi], rl[ni], ar[mi][ni]);
        ar[mi][ni] = mf(al[mi], rh[ni], ar[mi][ni]);
        av[mi][ni] = mf(ah[mi], vh[ni], av[mi][ni]);
        av[mi][ni] = mf(ah[mi], vl[ni], av[mi][ni]);
        av[mi][ni] = mf(al[mi], vh[ni], av[mi][ni]);
      }
  }
  const int col0 = lane & 15, row0 = (lane >> 4) * 4;
#pragma unroll
  for (int mi = 0; mi < 4; mi++)
#pragma unroll
    for (int ni = 0; ni < 2; ni++)
#pragma unroll
      for (int r = 0; r < 4; r++) {
        const int row = rowbase + wm + mi * 16 + row0 + r;
        const int col = colbase + wn + ni * 16 + col0;
        const size_t idx = (size_t)row * NC + col;
        const float g = sigf(ar[mi][ni][r]) * av[mi][ni][r];
        const u16 h = f2b(g);
        Ghi[idx] = h;
        Glo[idx] = f2b(g - b2f(h));
        G16[idx] = f2h(g);
      }
}

// ============ fp16 GEMM: Xnew = Xin(fp32) + A@Wo, tile 128x64 ================
__global__ __launch_bounds__(256) void gemm_wo_f16(
    const u16* __restrict__ A, const u16* __restrict__ BT, int K, int NC,
    const float* __restrict__ Xin, float* __restrict__ Xnew) {
  __shared__ __align__(16) u16 sA[4096], sB[2048];
  const int tid = threadIdx.x, lane = tid & 63, wave = tid >> 6;
  const int rowbase = blockIdx.y * 128, colbase = blockIdx.x * 64;
  const int wm = (wave >> 1) * 64, wn = (wave & 1) * 32;
  floatx4 acc[4][2] = {};
  const int c0 = tid, c1 = tid + 256;
  for (int k0 = 0; k0 < K; k0 += 32) {
    __syncthreads();
    stage2(sA, A, K, rowbase, c0, c1, k0);
    stage1(sB, BT, K, colbase, c0, k0);
    __syncthreads();
    const int fr = lane & 15, fk = (lane >> 4) * 8;
    half8 af[4], bf[2];
    fragN(af, sA, wm, fr, fk, 4);
    fragN(bf, sB, wn, fr, fk, 2);
#pragma unroll
    for (int mi = 0; mi < 4; mi++)
#pragma unroll
      for (int ni = 0; ni < 2; ni++)
        acc[mi][ni] = mfh(af[mi], bf[ni], acc[mi][ni]);
  }
  const int col0 = lane & 15, row0 = (lane >> 4) * 4;
#pragma unroll
  for (int mi = 0; mi < 4; mi++)
#pragma unroll
    for (int ni = 0; ni < 2; ni++)
#pragma unroll
      for (int r = 0; r < 4; r++) {
        const int row = rowbase + wm + mi * 16 + row0 + r;
        const int col = colbase + wn + ni * 16 + col0;
        const size_t idx = (size_t)row * NC + col;
        Xnew[idx] = Xin[idx] + acc[mi][ni][r];
      }
}

// ============ fused transformer-expert GEMMs: tg = (A1@B1)*sigmoid(A2@B2) ====
// A1 = h gathered, A2 = xln gathered (same idx). Output bf16 at local rows.
__global__ __launch_bounds__(256) void gemm_t12(
    const u16* __restrict__ A1, const u16* __restrict__ A2,
    const int* __restrict__ idxA,
    const u16* __restrict__ B1, const u16* __restrict__ B2, int K, int NC,
    const int* __restrict__ cntp, u16* __restrict__ Cout) {
  const int cnt = *cntp;
  if ((int)blockIdx.y * 128 >= cnt) return;
  __shared__ __align__(16) u16 s1[4096], s2[4096], sB1[4096], sB2[4096];
  const int tid = threadIdx.x, lane = tid & 63, wave = tid >> 6;
  const int rowbase = blockIdx.y * 128, colbase = blockIdx.x * 128;
  const int wm = (wave >> 1) * 64, wn = (wave & 1) * 64;
  floatx4 a1[4][4] = {}, a2[4][4] = {};
  const int c0 = tid, c1 = tid + 256;
  const int g0 = idxA[rowbase + (c0 >> 2)], g1 = idxA[rowbase + (c1 >> 2)];
  const u16* p10 = A1 + (size_t)g0 * K + (c0 & 3) * 8;
  const u16* p11 = A1 + (size_t)g1 * K + (c1 & 3) * 8;
  const u16* p20 = A2 + (size_t)g0 * K + (c0 & 3) * 8;
  const u16* p21 = A2 + (size_t)g1 * K + (c1 & 3) * 8;
  for (int k0 = 0; k0 < K; k0 += 32) {
    __syncthreads();
    gld16(s1 + c0 * 8, p10 + k0);
    gld16(s1 + c1 * 8, p11 + k0);
    gld16(s2 + c0 * 8, p20 + k0);
    gld16(s2 + c1 * 8, p21 + k0);
    stage2(sB1, B1, K, colbase, c0, c1, k0);
    stage2(sB2, B2, K, colbase, c0, c1, k0);
    __syncthreads();
    const int fr = lane & 15, fk = (lane >> 4) * 8;
    short8 f1[4], f2[4], b1[4], b2[4];
    fragN(f1, s1, wm, fr, fk, 4); fragN(f2, s2, wm, fr, fk, 4);
    fragN(b1, sB1, wn, fr, fk, 4); fragN(b2, sB2, wn, fr, fk, 4);
#pragma unroll
    for (int mi = 0; mi < 4; mi++)
#pragma unroll
      for (int ni = 0; ni < 4; ni++) {
        a1[mi][ni] = mf(f1[mi], b1[ni], a1[mi][ni]);
        a2[mi][ni] = mf(f2[mi], b2[ni], a2[mi][ni]);
      }
  }
  const int col0 = lane & 15, row0 = (lane >> 4) * 4;
#pragma unroll
  for (int mi = 0; mi < 4; mi++)
#pragma unroll
    for (int ni = 0; ni < 4; ni++)
#pragma unroll
      for (int r = 0; r < 4; r++) {
        const int row = rowbase + wm + mi * 16 + row0 + r;
        const int col = colbase + wn + ni * 16 + col0;
        Cout[(size_t)row * NC + col] =
            f2b(a1[mi][ni][r] * sigf(a2[mi][ni][r]));
      }
}

// ============ gathered/scattered plain bf16 GEMM, tile 128x128 ===============
template <int EPI>
__global__ __launch_bounds__(256) void ggemm(
    const u16* __restrict__ A, const int* __restrict__ idxA,
    const u16* __restrict__ BT, int K, int NC,
    const int* __restrict__ cntp, int base,
    u16* __restrict__ Cout,
    const float* __restrict__ x_new, const float* __restrict__ scalep,
    const int* __restrict__ idxO, float* __restrict__ out) {
  const int cnt = cntp ? (*cntp - base) : (int)(gridDim.y * 128);
  if ((int)blockIdx.y * 128 >= cnt) return;
  __shared__ __align__(16) u16 sA[4096], sB[4096];
  const int tid = threadIdx.x, lane = tid & 63, wave = tid >> 6;
  const int rowbase = blockIdx.y * 128, colbase = blockIdx.x * 128;
  const int wm = (wave >> 1) * 64, wn = (wave & 1) * 64;
  floatx4 acc[4][4] = {};
  const int c0 = tid, c1 = tid + 256;
  const int r0 = rowbase + (c0 >> 2), r1 = rowbase + (c1 >> 2);
  const int g0 = idxA ? idxA[base + r0] : r0;
  const int g1 = idxA ? idxA[base + r1] : r1;
  const u16* pA0 = A + (size_t)g0 * K + (c0 & 3) * 8;
  const u16* pA1 = A + (size_t)g1 * K + (c1 & 3) * 8;
  const u16* pB0 = BT + (size_t)(colbase + (c0 >> 2)) * K + (c0 & 3) * 8;
  const u16* pB1 = BT + (size_t)(colbase + (c1 >> 2)) * K + (c1 & 3) * 8;
  for (int k0 = 0; k0 < K; k0 += 32) {
    __syncthreads();
    gld16(sA + c0 * 8, pA0 + k0);
    gld16(sA + c1 * 8, pA1 + k0);
    gld16(sB + c0 * 8, pB0 + k0);
    gld16(sB + c1 * 8, pB1 + k0);
    __syncthreads();
    const int fr = lane & 15, fk = (lane >> 4) * 8;
    short8 af[4], bf[4];
    fragN(af, sA, wm, fr, fk, 4);
    fragN(bf, sB, wn, fr, fk, 4);
#pragma unroll
    for (int mi = 0; mi < 4; mi++)
#pragma unroll
      for (int ni = 0; ni < 4; ni++)
        acc[mi][ni] = mf(af[mi], bf[ni], acc[mi][ni]);
  }
  const int col0 = lane & 15, row00 = (lane >> 4) * 4;
#pragma unroll
  for (int mi = 0; mi < 4; mi++)
#pragma unroll
    for (int ni = 0; ni < 4; ni++)
#pragma unroll
      for (int r = 0; r < 4; r++) {
        const int row = rowbase + wm + mi * 16 + row00 + r;
        const int col = colbase + wn + ni * 16 + col0;
        const float v = acc[mi][ni][r];
        if constexpr (EPI == 0) {
          Cout[(size_t)row * NC + col] = f2b(v);
        } else if constexpr (EPI == 2) {
          const float t = v > 0.f ? v * v : 0.f;
          Cout[(size_t)row * NC + col] = f2b(t);
        } else {
          if (row < cnt) {
            const int g = idxO[base + row];
            const size_t o = (size_t)g * NC + col;
            out[o] = x_new[o] + v * scalep[g];
          }
        }
      }
}

// ============ fp32 -> bf16 (hi [,lo]) transpose ==============================
template <bool LO>
__global__ __launch_bounds__(256) void transpose_split(
    const float* __restrict__ in, u16* __restrict__ outh, u16* __restrict__ outl,
    int R, int Cc) {
  __shared__ float tile[32][33];
  const int tx = threadIdx.x & 31, ty = threadIdx.x >> 5;
  const int bx = blockIdx.x * 32, by = blockIdx.y * 32;
#pragma unroll
  for (int i = 0; i < 32; i += 8)
    tile[ty + i][tx] = in[(size_t)(by + ty + i) * Cc + bx + tx];
  __syncthreads();
#pragma unroll
  for (int i = 0; i < 32; i += 8) {
    const float v = tile[tx][ty + i];
    const size_t o = (size_t)(bx + ty + i) * R + by + tx;
    const u16 h = f2b(v);
    outh[o] = h;
    if constexpr (LO) outl[o] = f2b(v - b2f(h));
  }
}

// ============ fp32 -> fp16 transpose =========================================
__global__ __launch_bounds__(256) void transpose_f16(
    const float* __restrict__ in, u16* __restrict__ outh, int R, int Cc) {
  __shared__ float tile[32][33];
  const int tx = threadIdx.x & 31, ty = threadIdx.x >> 5;
  const int bx = blockIdx.x * 32, by = blockIdx.y * 32;
#pragma unroll
  for (int i = 0; i < 32; i += 8)
    tile[ty + i][tx] = in[(size_t)(by + ty + i) * Cc + bx + tx];
  __syncthreads();
#pragma unroll
  for (int i = 0; i < 32; i += 8)
    outh[(size_t)(bx + ty + i) * R + by + tx] = f2h(tile[tx][ty + i]);
}

// ============ fp32 -> bf16 straight cast =====================================
__global__ __launch_bounds__(256) void cast_kernel(const float* __restrict__ in,
                                                   u16* __restrict__ o, int n) {
  const int i = blockIdx.x * 256 + threadIdx.x;
  if (i < n) o[i] = f2b(in[i]);
}

// ============ LayerNorm fp32 -> bf16 hi + lo (LN1) ===========================
__global__ __launch_bounds__(256) void ln_kernel(
    const float* __restrict__ x, const float* __restrict__ w,
    const float* __restrict__ b, u16* __restrict__ oh, u16* __restrict__ ol) {
  const int row = blockIdx.x, tid = threadIdx.x;
  const float* xr = x + (size_t)row * C_DIM;
  float vals[4], s = 0.f, ss = 0.f;
#pragma unroll
  for (int i = 0; i < 4; i++) {
    const float t = xr[tid + i * 256];
    vals[i] = t; s += t; ss += t * t;
  }
  for (int off = 32; off; off >>= 1) {
    s += __shfl_xor(s, off, 64);
    ss += __shfl_xor(ss, off, 64);
  }
  __shared__ float red[8];
  const int lane = tid & 63, wave = tid >> 6;
  if (lane == 0) { red[wave] = s; red[4 + wave] = ss; }
  __syncthreads();
  const float S = red[0] + red[1] + red[2] + red[3];
  const float SS = red[4] + red[5] + red[6] + red[7];
  const float mean = S * (1.f / C_DIM);
  const float var = SS * (1.f / C_DIM) - mean * mean;
  const float inv = rsqrtf(var + 1e-5f);
#pragma unroll
  for (int i = 0; i < 4; i++) {
    const int c = tid + i * 256;
    const float y = (vals[i] - mean) * inv * w[c] + b[c];
    const u16 h = f2b(y);
    oh[(size_t)row * C_DIM + c] = h;
    ol[(size_t)row * C_DIM + c] = f2b(y - b2f(h));
  }
}

// ============ prep: p_j = ln2w * w_j ; g_j = sum(p_j) ; b_j = sum(ln2b*w_j) ==
__global__ __launch_bounds__(256) void prep_vec(
    const float* __restrict__ ln2w, const float* __restrict__ ln2b,
    const float* __restrict__ conf_rwkv, const float* __restrict__ conf_trans,
    const float* __restrict__ w_diff, const float* __restrict__ W_aff,
    float* __restrict__ p, float* __restrict__ sg, float* __restrict__ sb) {
  const int j = blockIdx.x, tid = threadIdx.x;
  float gs = 0.f, bs = 0.f;
#pragma unroll
  for (int i = 0; i < 4; i++) {
    const int c = tid + i * 256;
    float wv;
    if (j == 0) wv = conf_rwkv[c];
    else if (j == 1) wv = conf_rwkv[C_DIM + c];
    else if (j == 2) wv = conf_trans[c];
    else if (j == 3) wv = w_diff[c];
    else wv = W_aff[c * 3 + (j - 4)];
    const float pv = ln2w[c] * wv;
    p[j * C_DIM + c] = pv;
    gs += pv;
    bs += ln2b[c] * wv;
  }
  for (int off = 32; off; off >>= 1) {
    gs += __shfl_xor(gs, off, 64);
    bs += __shfl_xor(bs, off, 64);
  }
  __shared__ float red[8];
  const int lane = tid & 63, wave = tid >> 6;
  if (lane == 0) { red[wave] = gs; red[4 + wave] = bs; }
  __syncthreads();
  if (tid == 0) {
    sg[j] = red[0] + red[1] + red[2] + red[3];
    sb[j] = red[4] + red[5] + red[6] + red[7];
  }
}

// ============ u_j = Wo @ p_j  (fp32 GEMV, one wave per output element) =======
__global__ __launch_bounds__(256) void ugemv(
    const float* __restrict__ Wo, const float* __restrict__ p,
    float* __restrict__ u) {
  const int o = blockIdx.x * 4 + (threadIdx.x >> 6);
  const int lane = threadIdx.x & 63;
  const int j = o >> 10, k = o & 1023;
  float s = 0.f;
#pragma unroll
  for (int i = 0; i < 16; i++) {
    const int c = lane + i * 64;
    s += Wo[(size_t)k * C_DIM + c] * p[j * C_DIM + c];
  }
  for (int off = 32; off; off >>= 1) s += __shfl_xor(s, off, 64);
  if (lane == 0) u[o] = s;
}

// ============ routing: exact bids via decomposition; emits h (bf16) ==========
__global__ __launch_bounds__(256) void route_kernel(
    const float* __restrict__ x, const float* __restrict__ xn,
    const u16* __restrict__ ghi, const u16* __restrict__ glo,
    const float* __restrict__ p, const float* __restrict__ u,
    const float* __restrict__ sg, const float* __restrict__ sb,
    const float* __restrict__ ln2w, const float* __restrict__ ln2b,
    const float* __restrict__ capital,
    int* __restrict__ winner, float* __restrict__ scale, u16* __restrict__ oh) {
  const int token = blockIdx.x * 4 + (threadIdx.x >> 6);
  const int lane = threadIdx.x & 63;
  const float* xnr = xn + (size_t)token * C_DIM;
  float xv[16], s = 0.f, ss = 0.f;
#pragma unroll
  for (int i = 0; i < 16; i++) {
    const float t = xnr[lane + i * 64];
    xv[i] = t; s += t; ss += t * t;
  }
  for (int off = 32; off; off >>= 1) {
    s += __shfl_xor(s, off, 64);
    ss += __shfl_xor(ss, off, 64);
  }
  const float mean = s * (1.f / C_DIM);
  const float var = ss * (1.f / C_DIM) - mean * mean;
  const float inv = rsqrtf(var + 1e-5f);
  float acc[7] = {};
#pragma unroll
  for (int i = 0; i < 16; i++) {
    const int c = lane + i * 64;
    // h output for experts
    oh[(size_t)token * C_DIM + c] = f2b((xv[i] - mean) * inv * ln2w[c] + ln2b[c]);
    const float xc = x[(size_t)token * C_DIM + c];
    const float gc = b2f(ghi[(size_t)token * C_DIM + c]) +
                     b2f(glo[(size_t)token * C_DIM + c]);
#pragma unroll
    for (int j = 0; j < 7; j++)
      acc[j] += xc * p[j * C_DIM + c] + gc * u[j * C_DIM + c];
  }
  for (int off = 32; off; off >>= 1)
#pragma unroll
    for (int j = 0; j < 7; j++) acc[j] += __shfl_xor(acc[j], off, 64);
  if (lane == 0) {
    float hw[7];
#pragma unroll
    for (int j = 0; j < 7; j++) hw[j] = acc[j] * inv - mean * inv * sg[j] + sb[j];
    const float conf[3] = {1.f / (1.f + expf(-hw[0])), 1.f / (1.f + expf(-hw[1])),
                           1.f / (1.f + expf(-hw[2]))};
    const float diff = 1.f / (1.f + expf(-hw[3]));
    int best = 0; float bb = -1e30f;
#pragma unroll
    for (int e = 0; e < 3; e++) {
      const float bid = conf[e] * capital[e] * diff + hw[4 + e];
      if (bid > bb) { bb = bid; best = e; }  // first-max ties = jnp.argmax
    }
    winner[token] = best;
    scale[token] = conf[best] / (conf[best] + 1e-6f);
  }
}

// ============ compaction =====================================================
__global__ __launch_bounds__(256) void zero_kernel(int* __restrict__ pz, int n) {
  const int i = blockIdx.x * 256 + threadIdx.x;
  if (i < n) pz[i] = 0;
}
__global__ __launch_bounds__(256) void compact_kernel(
    const int* __restrict__ winner, int* __restrict__ idx, int* __restrict__ counts) {
  const int t = blockIdx.x * 256 + threadIdx.x;
  const int w = winner[t];
  const int pos = atomicAdd(counts + w, 1);
  idx[w * N_TOK + pos] = t;
}

extern "C" void kernel_launch(void* const* d_in, const int* in_sizes, int n_in,
                              void* d_out, int out_size, void* d_ws, size_t ws_size,
                              hipStream_t stream) {
  const float* x = (const float*)d_in[0];
  const float* capital = (const float*)d_in[2];
  const float* ln1w = (const float*)d_in[3];
  const float* ln1b = (const float*)d_in[4];
  const float* ln2w = (const float*)d_in[5];
  const float* ln2b = (const float*)d_in[6];
  const float* Wr = (const float*)d_in[7];
  const float* Wv = (const float*)d_in[8];
  const float* Wo = (const float*)d_in[9];
  const float* Wsm = (const float*)d_in[10];
  const float* Krwkv = (const float*)d_in[11];   // (2, C, H)
  const float* Vrwkv = (const float*)d_in[12];   // (2, H, C)
  const float* conf_rwkv = (const float*)d_in[13];
  const float* W1 = (const float*)d_in[14];
  const float* W2 = (const float*)d_in[15];
  const float* W3 = (const float*)d_in[16];
  const float* conf_trans = (const float*)d_in[17];
  const float* w_diff = (const float*)d_in[18];
  const float* W_aff = (const float*)d_in[19];
  float* out = (float*)d_out;

  char* ws = (char*)d_ws;
  size_t off = 0;
  auto alloc = [&](size_t bytes) -> char* {
    char* pp = ws + off;
    off += (bytes + 255) & ~(size_t)255;
    return pp;
  };
  const size_t CC = (size_t)C_DIM * C_DIM * 2;   // 2 MiB
  const size_t CH = (size_t)C_DIM * H_DIM * 2;   // 8 MiB
  const size_t NCb = (size_t)N_TOK * C_DIM * 2;  // 16 MiB
  u16* WrTh = (u16*)alloc(CC); u16* WrTl = (u16*)alloc(CC);
  u16* WvTh = (u16*)alloc(CC); u16* WvTl = (u16*)alloc(CC);
  u16* WoT16 = (u16*)alloc(CC);
  u16* W1T = (u16*)alloc(CC);
  u16* W2T = (u16*)alloc(CC);
  u16* W3T = (u16*)alloc(CC);
  u16* Wsb = (u16*)alloc(CC);
  u16* MT  = (u16*)alloc(CC);   // (Ws@W2)^T
  u16* KT0 = (u16*)alloc(CH);
  u16* VT0 = (u16*)alloc(CH);
  u16* KT1 = (u16*)alloc(CH);
  u16* VT1 = (u16*)alloc(CH);
  u16* xlnh = (u16*)alloc(NCb);   // LN1 hi (live through t12)
  u16* xlnl = (u16*)alloc(NCb);   // LN1 lo; reused as hb (h bf16) after rv
  u16* ghi = (u16*)alloc(NCb);    // gated hi; reused as tg after route
  u16* glo = (u16*)alloc(NCb);    // gated lo
  u16* g16 = (u16*)alloc(NCb);    // gated fp16 (Wo GEMM A)
  float* x_new = (float*)alloc((size_t)N_TOK * C_DIM * 4);  // 32 MiB
  u16* hr = (u16*)alloc((size_t)4096 * H_DIM * 2);          // 32 MiB chunk
  int* idx = (int*)alloc(3 * N_TOK * 4);   // contiguous with counts (both 256-aligned)
  int* counts = (int*)alloc(256);
  int* winner = (int*)alloc(N_TOK * 4);
  float* scalep = (float*)alloc(N_TOK * 4);
  float* pvec = (float*)alloc(7 * C_DIM * 4);
  float* uvec = (float*)alloc(7 * C_DIM * 4);
  float* sgv = (float*)alloc(256);
  float* sbv = (float*)alloc(256);

  const dim3 blk(256);
  const dim3 tCC(32, 32);
  transpose_split<true><<<tCC, blk, 0, stream>>>(Wr, WrTh, WrTl, C_DIM, C_DIM);
  transpose_split<true><<<tCC, blk, 0, stream>>>(Wv, WvTh, WvTl, C_DIM, C_DIM);
  transpose_f16<<<tCC, blk, 0, stream>>>(Wo, WoT16, C_DIM, C_DIM);
  transpose_split<false><<<tCC, blk, 0, stream>>>(W1, W1T, nullptr, C_DIM, C_DIM);
  transpose_split<false><<<tCC, blk, 0, stream>>>(W2, W2T, nullptr, C_DIM, C_DIM);
  transpose_split<false><<<tCC, blk, 0, stream>>>(W3, W3T, nullptr, C_DIM, C_DIM);
  cast_kernel<<<(C_DIM * C_DIM) / 256, blk, 0, stream>>>(Wsm, Wsb, C_DIM * C_DIM);
  transpose_split<false><<<dim3(H_DIM / 32, C_DIM / 32), blk, 0, stream>>>(
      Krwkv, KT0, nullptr, C_DIM, H_DIM);
  transpose_split<false><<<dim3(C_DIM / 32, H_DIM / 32), blk, 0, stream>>>(
      Vrwkv, VT0, nullptr, H_DIM, C_DIM);
  transpose_split<false><<<dim3(H_DIM / 32, C_DIM / 32), blk, 0, stream>>>(
      Krwkv + (size_t)C_DIM * H_DIM, KT1, nullptr, C_DIM, H_DIM);
  transpose_split<false><<<dim3(C_DIM / 32, H_DIM / 32), blk, 0, stream>>>(
      Vrwkv + (size_t)C_DIM * H_DIM, VT1, nullptr, H_DIM, C_DIM);
  // MT = W2T @ Wsb  -> (Ws@W2)^T
  ggemm<0><<<dim3(8, 8), blk, 0, stream>>>(W2T, nullptr, Wsb, C_DIM, C_DIM,
      nullptr, 0, MT, nullptr, nullptr, nullptr, nullptr);
  // routing-vector prep
  prep_vec<<<7, blk, 0, stream>>>(ln2w, ln2b, conf_rwkv, conf_trans, w_diff,
                                  W_aff, pvec, sgv, sbv);
  ugemv<<<7 * C_DIM / 4, blk, 0, stream>>>(Wo, pvec, uvec);

  // LN1 (split)
  ln_kernel<<<N_TOK, blk, 0, stream>>>(x, ln1w, ln1b, xlnh, xlnl);

  // gated = sigmoid(xln@Wr) * (xln@Wv)  (hi/lo + fp16), tile 128x64
  gemm_rv<<<dim3(C_DIM / 64, N_TOK / 128), blk, 0, stream>>>(
      xlnh, xlnl, WrTh, WrTl, WvTh, WvTl, C_DIM, C_DIM, ghi, glo, g16);
  // x_new = x + gated @ Wo (fp16 single pass), tile 128x64
  gemm_wo_f16<<<dim3(C_DIM / 64, N_TOK / 128), blk, 0, stream>>>(
      g16, WoT16, C_DIM, C_DIM, x, x_new);
  // routing: exact bids + h (bf16 into xlnl-reuse = hb)
  u16* hb = xlnl;
  route_kernel<<<N_TOK / 4, blk, 0, stream>>>(x, x_new, ghi, glo, pvec, uvec,
      sgv, sbv, ln2w, ln2b, capital, winner, scalep, hb);
  // compaction (zero idx AND the contiguous counts block)
  zero_kernel<<<(3 * N_TOK + 64 + 255) / 256, blk, 0, stream>>>(idx, 3 * N_TOK + 64);
  compact_kernel<<<N_TOK / 256, blk, 0, stream>>>(winner, idx, counts);

  // ---- transformer expert (e=2): tg = (h@W1)*sig(xln@MT), out |= tg@W3 ----
  int* idx2 = idx + 2 * N_TOK;
  u16* tg = ghi;  // ghi free after route
  const dim3 gC(C_DIM / 128, N_TOK / 128);
  gemm_t12<<<gC, blk, 0, stream>>>(hb, xlnh, idx2, W1T, MT, C_DIM, C_DIM,
                                   counts + 2, tg);
  ggemm<3><<<gC, blk, 0, stream>>>(tg, nullptr, W3T, C_DIM, C_DIM,
      counts + 2, 0, nullptr, x_new, scalep, idx2, out);

  // ---- RWKV experts (e=0,1), gathered, hr chunked 4096 rows ----
  const u16* KTa[2] = {KT0, KT1};
  const u16* VTa[2] = {VT0, VT1};
  for (int e = 0; e < 2; e++) {
    int* idxe = idx + e * N_TOK;
    for (int c = 0; c < 2; c++) {
      const int base = c * 4096;
      ggemm<2><<<dim3(H_DIM / 128, 32), blk, 0, stream>>>(
          hb, idxe, KTa[e], C_DIM, H_DIM, counts + e, base, hr,
          nullptr, nullptr, nullptr, nullptr);
      ggemm<3><<<dim3(C_DIM / 128, 32), blk, 0, stream>>>(
          hr, nullptr, VTa[e], H_DIM, C_DIM, counts + e, base, nullptr,
          x_new, scalep, idxe, out);
    }
  }
}